// Round 1
// baseline (141.429 us; speedup 1.0000x reference)
//
#include <hip/hip_runtime.h>

#define B_ 4
#define T_ 4096
#define E_ 1024
#define H_ 64

typedef __attribute__((ext_vector_type(8))) short short8;   // 8 x bf16 (4 VGPRs)
typedef __attribute__((ext_vector_type(4))) float f32x4;    // MFMA accumulator

static __device__ __forceinline__ unsigned short f2bf(float f) {
    unsigned int u = __builtin_bit_cast(unsigned int, f);
    u += 0x7fffu + ((u >> 16) & 1u);   // round-to-nearest-even
    return (unsigned short)(u >> 16);
}

// ---------------------------------------------------------------------------
// Kernel 1: transpose W [1024][64] f32 -> Wt [3][64][1024] bf16
// mat 0 = Wq, 1 = Wk, 2 = Wv. grid = 3*16 blocks, 256 threads.
// ---------------------------------------------------------------------------
__global__ __launch_bounds__(256) void wt_transpose_kernel(
    const float* __restrict__ Wq, const float* __restrict__ Wk,
    const float* __restrict__ Wv, unsigned short* __restrict__ Wt)
{
    __shared__ float tile[64][65];
    const int mat = blockIdx.x >> 4;
    const int kt  = blockIdx.x & 15;
    const float* W = (mat == 0) ? Wq : ((mat == 1) ? Wk : Wv);
    const int tid = threadIdx.x;
    #pragma unroll
    for (int p = 0; p < 16; ++p) {
        int idx = p * 256 + tid;
        tile[idx >> 6][idx & 63] = W[(kt * 64 + (idx >> 6)) * 64 + (idx & 63)];
    }
    __syncthreads();
    #pragma unroll
    for (int p = 0; p < 16; ++p) {
        int idx = p * 256 + tid;
        int h = idx >> 6, kl = idx & 63;
        Wt[(mat * 64 + h) * E_ + kt * 64 + kl] = f2bf(tile[kl][h]);
    }
}

// ---------------------------------------------------------------------------
// Kernel 2: fused QKV projection. x[16384][1024] f32 @ Wt -> Qb/Kb [16384][64]
// bf16 and Vt [4][64][4096] bf16 (V transposed for PV fragment loads).
// grid = 256 blocks (64 rows each), 256 threads (4 waves x 16 rows).
// mfma_f32_16x16x32_bf16: A row=lane&15,k=8*(lane>>4)+j ; B col=lane&15,same k;
// D col=lane&15,row=4*(lane>>4)+reg.
// ---------------------------------------------------------------------------
__global__ __launch_bounds__(256) void proj_kernel(
    const float* __restrict__ x, const unsigned short* __restrict__ Wt,
    unsigned short* __restrict__ Qb, unsigned short* __restrict__ Kb,
    unsigned short* __restrict__ Vt)
{
    __shared__ unsigned short wt_lds[192][72];   // +8 pad: bank-conflict relief
    const int tid  = threadIdx.x;
    const int wid  = tid >> 6, lane = tid & 63;
    const int g    = lane >> 4, c = lane & 15;
    const int r0   = blockIdx.x * 64;

    f32x4 acc[3][4];
    #pragma unroll
    for (int m = 0; m < 3; ++m)
        #pragma unroll
        for (int n = 0; n < 4; ++n) acc[m][n] = 0.0f;

    const float* xrow = x + (size_t)(r0 + wid * 16 + c) * E_;

    for (int kk = 0; kk < E_; kk += 64) {
        #pragma unroll
        for (int p = 0; p < 6; ++p) {               // stage 192x64 bf16 of Wt
            int cidx = p * 256 + tid;                // 1536 16B-chunks
            int kchunk = cidx & 7;
            int hrow = cidx >> 3;
            *(short8*)&wt_lds[hrow][kchunk * 8] =
                *(const short8*)&Wt[hrow * E_ + kk + kchunk * 8];
        }
        __syncthreads();
        #pragma unroll
        for (int kc = 0; kc < 2; ++kc) {
            f32x4 xa = *(const f32x4*)&xrow[kk + kc * 32 + 8 * g];
            f32x4 xb = *(const f32x4*)&xrow[kk + kc * 32 + 8 * g + 4];
            short8 a;
            #pragma unroll
            for (int j = 0; j < 4; ++j) {
                a[j]     = (short)f2bf(xa[j]);
                a[j + 4] = (short)f2bf(xb[j]);
            }
            #pragma unroll
            for (int m = 0; m < 3; ++m)
                #pragma unroll
                for (int n = 0; n < 4; ++n) {
                    short8 b = *(const short8*)&wt_lds[m * 64 + n * 16 + c][kc * 32 + 8 * g];
                    acc[m][n] = __builtin_amdgcn_mfma_f32_16x16x32_bf16(a, b, acc[m][n], 0, 0, 0);
                }
        }
        __syncthreads();
    }

    const int bb = r0 >> 12;                        // batch (no block straddles)
    #pragma unroll
    for (int n = 0; n < 4; ++n)
        #pragma unroll
        for (int r = 0; r < 4; ++r) {
            int row = r0 + wid * 16 + 4 * g + r;
            int col = n * 16 + c;
            Qb[(size_t)row * H_ + col] = f2bf(acc[0][n][r]);
            Kb[(size_t)row * H_ + col] = f2bf(acc[1][n][r]);
            Vt[((size_t)bb * H_ + col) * T_ + (row & (T_ - 1))] = f2bf(acc[2][n][r]);
        }
}

// ---------------------------------------------------------------------------
// Kernel 3: causal flash attention. One wave = one 16-row q-tile; KV tile = 64.
// grid = 4 batches * 64 blocks, 256 threads (4 waves). Block tile pairing
// {2k, 2k+1, 254-2k, 255-2k} for coarse load balance.
// ---------------------------------------------------------------------------
__global__ __launch_bounds__(256) void attn_kernel(
    const unsigned short* __restrict__ Qb, const unsigned short* __restrict__ Kb,
    const unsigned short* __restrict__ Vt, float* __restrict__ out)
{
    __shared__ unsigned short p_lds[4][16][72];     // per-wave P round-trip
    const int tid   = threadIdx.x;
    const int wid   = tid >> 6, lane = tid & 63;
    const int g     = lane >> 4, c = lane & 15;
    const int blk   = blockIdx.x & 63;
    const int batch = blockIdx.x >> 6;
    const int tile  = (wid < 2) ? (2 * blk + wid) : (254 - 2 * blk + (wid - 2));
    const int qbase = tile * 16;
    const float SCALE = 0.03125f * 1.44269504088896f;   // 1/sqrt(E) * log2(e)

    short8 aq0, aq1;                                // Q fragments (K=64 -> 2 chunks)
    {
        const unsigned short* qp = Qb + ((size_t)(batch * T_ + qbase + c)) * H_ + 8 * g;
        aq0 = *(const short8*)&qp[0];
        aq1 = *(const short8*)&qp[32];
    }

    f32x4 o_acc[4];
    #pragma unroll
    for (int n = 0; n < 4; ++n) o_acc[n] = 0.0f;
    float m_run[4], l_run[4];
    #pragma unroll
    for (int r = 0; r < 4; ++r) { m_run[r] = -1e30f; l_run[r] = 0.0f; }

    const int nkv = (qbase + 16 + 63) >> 6;
    for (int t = 0; t < nkv; ++t) {
        const int key0 = t * 64;

        // ---- S = Q K^T : 8 MFMAs; K frags direct from L2 (16B/lane) ----
        f32x4 s[4];
        #pragma unroll
        for (int n = 0; n < 4; ++n) s[n] = 0.0f;
        const unsigned short* kp = Kb + ((size_t)(batch * T_ + key0 + c)) * H_ + 8 * g;
        #pragma unroll
        for (int n = 0; n < 4; ++n) {
            short8 bk0 = *(const short8*)&kp[n * 16 * H_];
            short8 bk1 = *(const short8*)&kp[n * 16 * H_ + 32];
            s[n] = __builtin_amdgcn_mfma_f32_16x16x32_bf16(aq0, bk0, s[n], 0, 0, 0);
            s[n] = __builtin_amdgcn_mfma_f32_16x16x32_bf16(aq1, bk1, s[n], 0, 0, 0);
        }

        // ---- scale + causal mask (only last tile is ever partial) ----
        float sv[4][4];
        const bool maskt = (t == nkv - 1);
        #pragma unroll
        for (int n = 0; n < 4; ++n)
            #pragma unroll
            for (int r = 0; r < 4; ++r) {
                float v = s[n][r] * SCALE;
                if (maskt && (key0 + n * 16 + c) > (qbase + 4 * g + r)) v = -1e30f;
                sv[n][r] = v;
            }

        // ---- online softmax (exp2 domain); rows live in (g,r), cols in c ----
        float tmax[4];
        #pragma unroll
        for (int r = 0; r < 4; ++r)
            tmax[r] = fmaxf(fmaxf(sv[0][r], sv[1][r]), fmaxf(sv[2][r], sv[3][r]));
        #pragma unroll
        for (int off = 1; off < 16; off <<= 1)
            #pragma unroll
            for (int r = 0; r < 4; ++r)
                tmax[r] = fmaxf(tmax[r], __shfl_xor(tmax[r], off));

        float fac[4], mnew[4];
        #pragma unroll
        for (int r = 0; r < 4; ++r) {
            mnew[r]  = fmaxf(m_run[r], tmax[r]);
            fac[r]   = exp2f(m_run[r] - mnew[r]);
            m_run[r] = mnew[r];
        }
        float rsum[4] = {0.f, 0.f, 0.f, 0.f};
        #pragma unroll
        for (int n = 0; n < 4; ++n)
            #pragma unroll
            for (int r = 0; r < 4; ++r) {
                float p = exp2f(sv[n][r] - mnew[r]);
                sv[n][r] = p;
                rsum[r] += p;
            }
        #pragma unroll
        for (int off = 1; off < 16; off <<= 1)
            #pragma unroll
            for (int r = 0; r < 4; ++r)
                rsum[r] += __shfl_xor(rsum[r], off);
        #pragma unroll
        for (int r = 0; r < 4; ++r)
            l_run[r] = l_run[r] * fac[r] + rsum[r];
        #pragma unroll
        for (int n = 0; n < 4; ++n)
            #pragma unroll
            for (int r = 0; r < 4; ++r)
                o_acc[n][r] *= fac[r];

        // ---- P: D-layout -> A-frag layout via per-wave LDS (in-order DS) ----
        #pragma unroll
        for (int n = 0; n < 4; ++n)
            #pragma unroll
            for (int r = 0; r < 4; ++r)
                p_lds[wid][4 * g + r][n * 16 + c] = f2bf(sv[n][r]);

        short8 pa0 = *(const short8*)&p_lds[wid][c][8 * g];
        short8 pa1 = *(const short8*)&p_lds[wid][c][32 + 8 * g];

        // ---- O += P V : V^T frags contiguous from Vt ----
        const unsigned short* vp = Vt + ((size_t)(batch * H_ + c)) * T_ + key0 + 8 * g;
        #pragma unroll
        for (int n = 0; n < 4; ++n) {
            short8 bv0 = *(const short8*)&vp[(size_t)n * 16 * T_];
            short8 bv1 = *(const short8*)&vp[(size_t)n * 16 * T_ + 32];
            o_acc[n] = __builtin_amdgcn_mfma_f32_16x16x32_bf16(pa0, bv0, o_acc[n], 0, 0, 0);
            o_acc[n] = __builtin_amdgcn_mfma_f32_16x16x32_bf16(pa1, bv1, o_acc[n], 0, 0, 0);
        }
    }

    float* op = out + ((size_t)(batch * T_ + qbase + 4 * g)) * H_;
    #pragma unroll
    for (int r = 0; r < 4; ++r) {
        float inv = 1.0f / l_run[r];
        #pragma unroll
        for (int n = 0; n < 4; ++n)
            op[r * H_ + n * 16 + c] = o_acc[n][r] * inv;
    }
}

// ---------------------------------------------------------------------------
extern "C" void kernel_launch(void* const* d_in, const int* in_sizes, int n_in,
                              void* d_out, int out_size, void* d_ws, size_t ws_size,
                              hipStream_t stream)
{
    const float* x  = (const float*)d_in[0];
    const float* Wk = (const float*)d_in[1];
    const float* Wq = (const float*)d_in[2];
    const float* Wv = (const float*)d_in[3];
    float* out = (float*)d_out;

    // workspace: Wt (3*64*1024) | Qb | Kb | Vt  (all bf16)  ~6.5 MB total
    unsigned short* Wt = (unsigned short*)d_ws;
    unsigned short* Qb = Wt + 3 * 64 * 1024;
    unsigned short* Kb = Qb + (size_t)B_ * T_ * H_;
    unsigned short* Vt = Kb + (size_t)B_ * T_ * H_;

    hipLaunchKernelGGL(wt_transpose_kernel, dim3(48), dim3(256), 0, stream, Wq, Wk, Wv, Wt);
    hipLaunchKernelGGL(proj_kernel, dim3(256), dim3(256), 0, stream, x, Wt, Qb, Kb, Vt);
    hipLaunchKernelGGL(attn_kernel, dim3(B_ * 64), dim3(256), 0, stream, Qb, Kb, Vt, out);
}

// Round 2
// 139.782 us; speedup vs baseline: 1.0118x; 1.0118x over previous
//
#include <hip/hip_runtime.h>

#define B_ 4
#define T_ 4096
#define E_ 1024
#define H_ 64

typedef __attribute__((ext_vector_type(8))) short short8;   // 8 x bf16 (4 VGPRs)
typedef __attribute__((ext_vector_type(4))) float f32x4;    // MFMA accumulator

static __device__ __forceinline__ unsigned short f2bf(float f) {
    unsigned int u = __builtin_bit_cast(unsigned int, f);
    u += 0x7fffu + ((u >> 16) & 1u);   // round-to-nearest-even
    return (unsigned short)(u >> 16);
}
static __device__ __forceinline__ float bf2f(unsigned short h) {
    unsigned int u = ((unsigned int)h) << 16;
    return __builtin_bit_cast(float, u);
}

// ---------------------------------------------------------------------------
// Kernel 1: transpose W [1024][64] f32 -> Wt [3][64][1024] bf16
// ---------------------------------------------------------------------------
__global__ __launch_bounds__(256) void wt_transpose_kernel(
    const float* __restrict__ Wq, const float* __restrict__ Wk,
    const float* __restrict__ Wv, unsigned short* __restrict__ Wt)
{
    __shared__ float tile[64][65];
    const int mat = blockIdx.x >> 4;
    const int kt  = blockIdx.x & 15;
    const float* W = (mat == 0) ? Wq : ((mat == 1) ? Wk : Wv);
    const int tid = threadIdx.x;
    #pragma unroll
    for (int p = 0; p < 16; ++p) {
        int idx = p * 256 + tid;
        tile[idx >> 6][idx & 63] = W[(kt * 64 + (idx >> 6)) * 64 + (idx & 63)];
    }
    __syncthreads();
    #pragma unroll
    for (int p = 0; p < 16; ++p) {
        int idx = p * 256 + tid;
        int h = idx >> 6, kl = idx & 63;
        Wt[(mat * 64 + h) * E_ + kt * 64 + kl] = f2bf(tile[kl][h]);
    }
}

// ---------------------------------------------------------------------------
// Kernel 2: fused QKV projection (unchanged this round).
// ---------------------------------------------------------------------------
__global__ __launch_bounds__(256) void proj_kernel(
    const float* __restrict__ x, const unsigned short* __restrict__ Wt,
    unsigned short* __restrict__ Qb, unsigned short* __restrict__ Kb,
    unsigned short* __restrict__ Vt)
{
    __shared__ unsigned short wt_lds[192][72];
    const int tid  = threadIdx.x;
    const int wid  = tid >> 6, lane = tid & 63;
    const int g    = lane >> 4, c = lane & 15;
    const int r0   = blockIdx.x * 64;

    f32x4 acc[3][4];
    #pragma unroll
    for (int m = 0; m < 3; ++m)
        #pragma unroll
        for (int n = 0; n < 4; ++n) acc[m][n] = 0.0f;

    const float* xrow = x + (size_t)(r0 + wid * 16 + c) * E_;

    for (int kk = 0; kk < E_; kk += 64) {
        #pragma unroll
        for (int p = 0; p < 6; ++p) {
            int cidx = p * 256 + tid;
            int kchunk = cidx & 7;
            int hrow = cidx >> 3;
            *(short8*)&wt_lds[hrow][kchunk * 8] =
                *(const short8*)&Wt[hrow * E_ + kk + kchunk * 8];
        }
        __syncthreads();
        #pragma unroll
        for (int kc = 0; kc < 2; ++kc) {
            f32x4 xa = *(const f32x4*)&xrow[kk + kc * 32 + 8 * g];
            f32x4 xb = *(const f32x4*)&xrow[kk + kc * 32 + 8 * g + 4];
            short8 a;
            #pragma unroll
            for (int j = 0; j < 4; ++j) {
                a[j]     = (short)f2bf(xa[j]);
                a[j + 4] = (short)f2bf(xb[j]);
            }
            #pragma unroll
            for (int m = 0; m < 3; ++m)
                #pragma unroll
                for (int n = 0; n < 4; ++n) {
                    short8 b = *(const short8*)&wt_lds[m * 64 + n * 16 + c][kc * 32 + 8 * g];
                    acc[m][n] = __builtin_amdgcn_mfma_f32_16x16x32_bf16(a, b, acc[m][n], 0, 0, 0);
                }
        }
        __syncthreads();
    }

    const int bb = r0 >> 12;
    #pragma unroll
    for (int n = 0; n < 4; ++n)
        #pragma unroll
        for (int r = 0; r < 4; ++r) {
            int row = r0 + wid * 16 + 4 * g + r;
            int col = n * 16 + c;
            Qb[(size_t)row * H_ + col] = f2bf(acc[0][n][r]);
            Kb[(size_t)row * H_ + col] = f2bf(acc[1][n][r]);
            Vt[((size_t)bb * H_ + col) * T_ + (row & (T_ - 1))] = f2bf(acc[2][n][r]);
        }
}

// ---------------------------------------------------------------------------
// Kernel 3: split-K flash attention. One wave = one (q-tile, kv-chunk) with
// chunk = 8 kv-tiles (512 keys). Partials (o bf16, m/l f32) go to workspace.
// Slot layout is compact: slot = batch*1152 + base(qt) + ch, where
// base(qt) = 4*S(n-1) + (qt&3)*ceil(n/8), n = (qt>>2)+1,
// S(M) = sum_{m=1..M} ceil(m/8) = 4*a*(a+1) + r*(a+1), a=M>>3, r=M&7.
// grid = 2048 blocks x 256 threads; inactive (qt,ch) slots exit immediately.
// Block's 4 waves = 4 consecutive qt with SAME chunk -> identical trip counts.
// ---------------------------------------------------------------------------
__global__ __launch_bounds__(256) void attn_split_kernel(
    const unsigned short* __restrict__ Qb, const unsigned short* __restrict__ Kb,
    const unsigned short* __restrict__ Vt, unsigned short* __restrict__ Po,
    float* __restrict__ Pm, float* __restrict__ Pl)
{
    __shared__ unsigned short p_lds[4][16][72];
    const int tid   = threadIdx.x;
    const int wid   = tid >> 6, lane = tid & 63;
    const int g     = lane >> 4, c = lane & 15;

    const int s     = blockIdx.x * 4 + wid;      // [0, 8192)
    const int batch = s >> 11;
    const int rem   = s & 2047;
    const int ch    = rem >> 8;                  // kv-chunk [0,8)
    const int qt    = rem & 255;                 // q-tile   [0,256)
    const int nkv   = (qt >> 2) + 1;             // total kv tiles for this qt
    if (ch * 8 >= nkv) return;                   // inactive slot
    const int nt    = min(8, nkv - ch * 8);      // tiles in this chunk
    const int qbase = qt * 16;

    const int Mm = nkv - 1, aa = Mm >> 3, rr8 = Mm & 7;
    const int npart = (nkv + 7) >> 3;
    const int slot  = batch * 1152 + 4 * (4 * aa * (aa + 1) + rr8 * (aa + 1))
                    + (qt & 3) * npart + ch;

    const float SCALE = 0.03125f * 1.44269504088896f;   // 1/sqrt(E) * log2(e)

    short8 aq0, aq1;
    {
        const unsigned short* qp = Qb + ((size_t)(batch * T_ + qbase + c)) * H_ + 8 * g;
        aq0 = *(const short8*)&qp[0];
        aq1 = *(const short8*)&qp[32];
    }

    f32x4 o_acc[4];
    #pragma unroll
    for (int n = 0; n < 4; ++n) o_acc[n] = 0.0f;
    float m_run[4], l_run[4];
    #pragma unroll
    for (int r = 0; r < 4; ++r) { m_run[r] = -1e30f; l_run[r] = 0.0f; }

    for (int t = 0; t < nt; ++t) {
        const int gtile = ch * 8 + t;
        const int key0  = gtile * 64;

        // ---- S = Q K^T ----
        f32x4 sAcc[4];
        #pragma unroll
        for (int n = 0; n < 4; ++n) sAcc[n] = 0.0f;
        const unsigned short* kp = Kb + ((size_t)(batch * T_ + key0 + c)) * H_ + 8 * g;
        #pragma unroll
        for (int n = 0; n < 4; ++n) {
            short8 bk0 = *(const short8*)&kp[n * 16 * H_];
            short8 bk1 = *(const short8*)&kp[n * 16 * H_ + 32];
            sAcc[n] = __builtin_amdgcn_mfma_f32_16x16x32_bf16(aq0, bk0, sAcc[n], 0, 0, 0);
            sAcc[n] = __builtin_amdgcn_mfma_f32_16x16x32_bf16(aq1, bk1, sAcc[n], 0, 0, 0);
        }

        // ---- scale + causal mask (only the global diagonal tile is partial) ----
        float sv[4][4];
        const bool maskt = (gtile == nkv - 1);
        #pragma unroll
        for (int n = 0; n < 4; ++n)
            #pragma unroll
            for (int r = 0; r < 4; ++r) {
                float v = sAcc[n][r] * SCALE;
                if (maskt && (key0 + n * 16 + c) > (qbase + 4 * g + r)) v = -1e30f;
                sv[n][r] = v;
            }

        // ---- online softmax (exp2 domain) ----
        float tmax[4];
        #pragma unroll
        for (int r = 0; r < 4; ++r)
            tmax[r] = fmaxf(fmaxf(sv[0][r], sv[1][r]), fmaxf(sv[2][r], sv[3][r]));
        #pragma unroll
        for (int off = 1; off < 16; off <<= 1)
            #pragma unroll
            for (int r = 0; r < 4; ++r)
                tmax[r] = fmaxf(tmax[r], __shfl_xor(tmax[r], off));

        float fac[4], mnew[4];
        #pragma unroll
        for (int r = 0; r < 4; ++r) {
            mnew[r]  = fmaxf(m_run[r], tmax[r]);
            fac[r]   = exp2f(m_run[r] - mnew[r]);
            m_run[r] = mnew[r];
        }
        float rsum[4] = {0.f, 0.f, 0.f, 0.f};
        #pragma unroll
        for (int n = 0; n < 4; ++n)
            #pragma unroll
            for (int r = 0; r < 4; ++r) {
                float p = exp2f(sv[n][r] - mnew[r]);
                sv[n][r] = p;
                rsum[r] += p;
            }
        #pragma unroll
        for (int off = 1; off < 16; off <<= 1)
            #pragma unroll
            for (int r = 0; r < 4; ++r)
                rsum[r] += __shfl_xor(rsum[r], off);
        #pragma unroll
        for (int r = 0; r < 4; ++r)
            l_run[r] = l_run[r] * fac[r] + rsum[r];
        #pragma unroll
        for (int n = 0; n < 4; ++n)
            #pragma unroll
            for (int r = 0; r < 4; ++r)
                o_acc[n][r] *= fac[r];

        // ---- P: D-layout -> A-frag layout via per-wave LDS ----
        #pragma unroll
        for (int n = 0; n < 4; ++n)
            #pragma unroll
            for (int r = 0; r < 4; ++r)
                p_lds[wid][4 * g + r][n * 16 + c] = f2bf(sv[n][r]);

        short8 pa0 = *(const short8*)&p_lds[wid][c][8 * g];
        short8 pa1 = *(const short8*)&p_lds[wid][c][32 + 8 * g];

        // ---- O += P V ----
        const unsigned short* vp = Vt + ((size_t)(batch * H_ + c)) * T_ + key0 + 8 * g;
        #pragma unroll
        for (int n = 0; n < 4; ++n) {
            short8 bv0 = *(const short8*)&vp[(size_t)n * 16 * T_];
            short8 bv1 = *(const short8*)&vp[(size_t)n * 16 * T_ + 32];
            o_acc[n] = __builtin_amdgcn_mfma_f32_16x16x32_bf16(pa0, bv0, o_acc[n], 0, 0, 0);
            o_acc[n] = __builtin_amdgcn_mfma_f32_16x16x32_bf16(pa1, bv1, o_acc[n], 0, 0, 0);
        }
    }

    // ---- store partial: o (bf16, unnormalized), m, l (f32) ----
    unsigned short* po = Po + (size_t)slot * 1024;
    #pragma unroll
    for (int n = 0; n < 4; ++n)
        #pragma unroll
        for (int r = 0; r < 4; ++r)
            po[(4 * g + r) * 64 + n * 16 + c] = f2bf(o_acc[n][r]);
    if (c == 0) {
        #pragma unroll
        for (int r = 0; r < 4; ++r) {
            Pm[slot * 16 + 4 * g + r] = m_run[r];
            Pl[slot * 16 + 4 * g + r] = l_run[r];
        }
    }
}

// ---------------------------------------------------------------------------
// Kernel 4: merge partials. One wave per q-tile; lane = (row, col-segment).
// grid = 256 blocks x 256 threads (1024 waves).
// ---------------------------------------------------------------------------
__global__ __launch_bounds__(256) void attn_merge_kernel(
    const unsigned short* __restrict__ Po, const float* __restrict__ Pm,
    const float* __restrict__ Pl, float* __restrict__ out)
{
    const int tid  = threadIdx.x;
    const int wid  = tid >> 6, lane = tid & 63;
    const int gi   = blockIdx.x * 4 + wid;       // [0, 1024)
    const int batch = gi >> 8, qt = gi & 255;
    const int nkv  = (qt >> 2) + 1;
    const int npart = (nkv + 7) >> 3;
    const int Mm = nkv - 1, aa = Mm >> 3, rr8 = Mm & 7;
    const int slot0 = batch * 1152 + 4 * (4 * aa * (aa + 1) + rr8 * (aa + 1))
                    + (qt & 3) * npart;

    const int row = lane & 15, seg = lane >> 4;

    float mrow = -1e30f;
    for (int i = 0; i < npart; ++i)
        mrow = fmaxf(mrow, Pm[(slot0 + i) * 16 + row]);

    float lacc = 0.0f, o[16];
    #pragma unroll
    for (int k = 0; k < 16; ++k) o[k] = 0.0f;

    for (int i = 0; i < npart; ++i) {
        const float w = exp2f(Pm[(slot0 + i) * 16 + row] - mrow);
        lacc += Pl[(slot0 + i) * 16 + row] * w;
        const unsigned short* pp = Po + (size_t)(slot0 + i) * 1024 + row * 64 + seg * 16;
        short8 v0 = *(const short8*)&pp[0];
        short8 v1 = *(const short8*)&pp[8];
        #pragma unroll
        for (int k = 0; k < 8; ++k) {
            o[k]     += bf2f((unsigned short)v0[k]) * w;
            o[8 + k] += bf2f((unsigned short)v1[k]) * w;
        }
    }

    const float inv = 1.0f / lacc;
    float* op = out + ((size_t)(batch * T_ + qt * 16 + row)) * H_ + seg * 16;
    #pragma unroll
    for (int k = 0; k < 16; ++k) op[k] = o[k] * inv;
}

// ---------------------------------------------------------------------------
extern "C" void kernel_launch(void* const* d_in, const int* in_sizes, int n_in,
                              void* d_out, int out_size, void* d_ws, size_t ws_size,
                              hipStream_t stream)
{
    const float* x  = (const float*)d_in[0];
    const float* Wk = (const float*)d_in[1];
    const float* Wq = (const float*)d_in[2];
    const float* Wv = (const float*)d_in[3];
    float* out = (float*)d_out;

    // workspace layout (bytes):
    //   Wt  [3*64*1024] bf16            384 KB
    //   Qb  [B*T*H] bf16                  2 MB
    //   Kb  [B*T*H] bf16                  2 MB
    //   Vt  [B*H*T] bf16                  2 MB
    //   Po  [4608][16][64] bf16         9.4 MB   (split-K partial o)
    //   Pm  [4608][16] f32              295 KB
    //   Pl  [4608][16] f32              295 KB   total ~16.4 MB
    unsigned short* Wt = (unsigned short*)d_ws;
    unsigned short* Qb = Wt + 3 * 64 * 1024;
    unsigned short* Kb = Qb + (size_t)B_ * T_ * H_;
    unsigned short* Vt = Kb + (size_t)B_ * T_ * H_;
    unsigned short* Po = Vt + (size_t)B_ * T_ * H_;
    float* Pm = (float*)(Po + (size_t)4608 * 1024);
    float* Pl = Pm + 4608 * 16;

    hipLaunchKernelGGL(wt_transpose_kernel, dim3(48), dim3(256), 0, stream, Wq, Wk, Wv, Wt);
    hipLaunchKernelGGL(proj_kernel, dim3(256), dim3(256), 0, stream, x, Wt, Qb, Kb, Vt);
    hipLaunchKernelGGL(attn_split_kernel, dim3(2048), dim3(256), 0, stream, Qb, Kb, Vt, Po, Pm, Pl);
    hipLaunchKernelGGL(attn_merge_kernel, dim3(256), dim3(256), 0, stream, Po, Pm, Pl, out);
}